// Round 14
// baseline (133.529 us; speedup 1.0000x reference)
//
#include <hip/hip_runtime.h>
#include <hip/hip_bf16.h>
#include <cstddef>

// Problem constants
#define BSZ 8
#define T_  8
#define L_  196
#define D_  192
#define E_  192
#define C_  1536   // E*T
#define N_  16
#define K_  4
#define R_  96

typedef __attribute__((ext_vector_type(8))) short short8;
typedef __attribute__((ext_vector_type(4))) float f32x4;
typedef unsigned short ushort_t;

__device__ __forceinline__ ushort_t f2bf(float x) {
  unsigned int bits = __float_as_uint(x);
  bits += 0x7FFFu + ((bits >> 16) & 1u);   // RNE
  return (ushort_t)(bits >> 16);
}

// ---------------- Kernel 0: fused fp32 -> bf16 cast (hidden + in_proj_w + dt_proj_w + x_proj_w) ----------------
__global__ __launch_bounds__(256) void k_cast_all(
    const float* __restrict__ hidden, const float* __restrict__ w,
    const float* __restrict__ wdt, const float* __restrict__ wx,
    ushort_t* __restrict__ hb, ushort_t* __restrict__ wb,
    ushort_t* __restrict__ wdtb, ushort_t* __restrict__ wxb) {
  const int H8 = 301056;           // 2408448/8 hidden
  const int W8 = H8 + 9216;        // + 73728/8 in_proj_w
  const int D8 = W8 + 18432;       // + 147456/8 dt_proj_w
  const int T8 = D8 + 24576;       // + 196608/8 x_proj_w
  int i = blockIdx.x * 256 + threadIdx.x;
  if (i >= T8) return;
  const float4* ip; uint4* op; int j;
  if (i < H8)      { ip = (const float4*)hidden; op = (uint4*)hb;   j = i; }
  else if (i < W8) { ip = (const float4*)w;      op = (uint4*)wb;   j = i - H8; }
  else if (i < D8) { ip = (const float4*)wdt;    op = (uint4*)wdtb; j = i - W8; }
  else             { ip = (const float4*)wx;     op = (uint4*)wxb;  j = i - D8; }
  float4 v0 = ip[(size_t)j * 2];
  float4 v1 = ip[(size_t)j * 2 + 1];
  union { ushort_t u[8]; uint4 v; } r;
  float f[8] = {v0.x, v0.y, v0.z, v0.w, v1.x, v1.y, v1.z, v1.w};
#pragma unroll
  for (int k = 0; k < 8; k++) r.u[k] = f2bf(f[k]);
  op[j] = r.v;
}

// ---------------- Kernel 1: in_proj GEMM via MFMA (bf16) ----------------
__global__ __launch_bounds__(256) void k_inproj_mfma(
    const ushort_t* __restrict__ hb, const ushort_t* __restrict__ wb,
    float* __restrict__ xb, float* __restrict__ zb) {
  __shared__ float smem[64][97];
  int tid = threadIdx.x;
  int wave = tid >> 6, lane = tid & 63;
  int m0b = blockIdx.x * 64;
  int n0 = blockIdx.y * 96;
  int row = lane & 15, kg = lane >> 4;
  int m0w = m0b + wave * 16;

  f32x4 acc[6] = {};
  const ushort_t* ap = hb + (size_t)(m0w + row) * 192 + kg * 8;
#pragma unroll
  for (int ks = 0; ks < 6; ks++) {
    short8 a = *(const short8*)(ap + ks * 32);
#pragma unroll
    for (int nt = 0; nt < 6; nt++) {
      short8 b = *(const short8*)(wb + (size_t)(n0 + nt * 16 + row) * 192 + ks * 32 + kg * 8);
      acc[nt] = __builtin_amdgcn_mfma_f32_16x16x32_bf16(a, b, acc[nt], 0, 0, 0);
    }
  }
#pragma unroll
  for (int nt = 0; nt < 6; nt++) {
#pragma unroll
    for (int j = 0; j < 4; j++) {
      smem[wave * 16 + kg * 4 + j][nt * 16 + row] = acc[nt][j];
    }
  }
  __syncthreads();
  int mloc = tid & 63, eof = tid >> 6;
  int m_glob = m0b + mloc;
  int b = m_glob / 1568, u = m_glob % 1568;
  size_t obase = (size_t)b * 301056 + u;   // b*C*L + u
#pragma unroll
  for (int e = eof; e < 96; e += 4) {
    int eg = n0 + e;
    float v = smem[mloc][e];
    if (eg < 192) xb[obase + (size_t)eg * 1568] = v;
    else          zb[obase + (size_t)(eg - 192) * 1568] = v;
  }
}

// ---------------- Kernel 1-fallback: fp32 in_proj (128x128 tile) ----------------
__global__ __launch_bounds__(256) void k_inproj_f32(
    const float* __restrict__ A, const float* __restrict__ W,
    float* __restrict__ xb, float* __restrict__ zb) {
  __shared__ float As[16][132];
  __shared__ float Bs[16][132];
  int tid = threadIdx.x;
  int m0 = blockIdx.x * 128;
  int n0 = blockIdx.y * 128;
  int tx = tid & 15, ty = tid >> 4;
  float acc[8][8] = {};
  for (int k0 = 0; k0 < 192; k0 += 16) {
#pragma unroll
    for (int i = 0; i < 2; i++) {
      int idx = tid + i * 256;
      int m = idx >> 2, k4 = (idx & 3) * 4;
      float4 v = *(const float4*)&A[(size_t)(m0 + m) * 192 + k0 + k4];
      As[k4 + 0][m] = v.x; As[k4 + 1][m] = v.y;
      As[k4 + 2][m] = v.z; As[k4 + 3][m] = v.w;
    }
#pragma unroll
    for (int i = 0; i < 2; i++) {
      int idx = tid + i * 256;
      int n = idx >> 2, k4 = (idx & 3) * 4;
      float4 v = *(const float4*)&W[(size_t)(n0 + n) * 192 + k0 + k4];
      Bs[k4 + 0][n] = v.x; Bs[k4 + 1][n] = v.y;
      Bs[k4 + 2][n] = v.z; Bs[k4 + 3][n] = v.w;
    }
    __syncthreads();
#pragma unroll
    for (int kk = 0; kk < 16; kk++) {
      float a_[8], b_[8];
      *(float4*)&a_[0] = *(const float4*)&As[kk][ty * 4];
      *(float4*)&a_[4] = *(const float4*)&As[kk][ty * 4 + 64];
      *(float4*)&b_[0] = *(const float4*)&Bs[kk][tx * 4];
      *(float4*)&b_[4] = *(const float4*)&Bs[kk][tx * 4 + 64];
#pragma unroll
      for (int i = 0; i < 8; i++)
#pragma unroll
        for (int j = 0; j < 8; j++) acc[i][j] += a_[i] * b_[j];
    }
    __syncthreads();
  }
#pragma unroll
  for (int i = 0; i < 8; i++) {
    int m = m0 + ty * 4 + (i & 3) + ((i >> 2) * 64);
    int b = m / (T_ * L_);
    int r = m % (T_ * L_);
    int t = r / L_;
    int l = r % L_;
#pragma unroll
    for (int j = 0; j < 8; j++) {
      int e = n0 + tx * 4 + (j & 3) + ((j >> 2) * 64);
      float v = acc[i][j];
      if (e < E_) {
        int c = e * T_ + t;
        xb[((size_t)b * C_ + c) * L_ + l] = v;
      } else {
        int c = (e - E_) * T_ + t;
        zb[((size_t)b * C_ + c) * L_ + l] = v;
      }
    }
  }
}

// ---------------- Kernel 2: conv + bias + SiLU -> xc (f32) and xcb (bf16, [n][c]) ----------------
// block: 64 c x 32 l for one b; LDS transpose for the [n][c] write.
__global__ __launch_bounds__(256) void k_conv_cast(
    const float* __restrict__ xb, const float* __restrict__ conv_w,
    const float* __restrict__ conv_b, float* __restrict__ xc,
    ushort_t* __restrict__ xcb) {
  __shared__ float sm[64][33];
  int tid = threadIdx.x;
  int l0 = blockIdx.x * 32;
  int c0 = blockIdx.y * 64;
  int b  = blockIdx.z;
  int c_loc = tid >> 2, lq = tid & 3;
  int c = c0 + c_loc;
  const float* xrow = xb + ((size_t)b * C_ + c) * L_;
  float* xcrow = xc + ((size_t)b * C_ + c) * L_;
  float w0 = conv_w[c * K_ + 0], w1 = conv_w[c * K_ + 1];
  float w2 = conv_w[c * K_ + 2], w3 = conv_w[c * K_ + 3];
  float cb = conv_b[c];
#pragma unroll
  for (int i = 0; i < 8; i++) {
    int l = l0 + lq * 8 + i;
    if (l < L_) {
      float s = cb;
      if (l >= 3) s += xrow[l - 3] * w0;
      if (l >= 2) s += xrow[l - 2] * w1;
      if (l >= 1) s += xrow[l - 1] * w2;
      s += xrow[l] * w3;
      float v = s / (1.f + __expf(-s));
      xcrow[l] = v;
      sm[c_loc][lq * 8 + i] = v;
    }
  }
  __syncthreads();
  int l_loc = tid >> 3, cg = tid & 7;
  int l = l0 + l_loc;
  if (l < L_) {
    int n = b * L_ + l;
    union { ushort_t u[8]; uint4 v; } r;
#pragma unroll
    for (int i = 0; i < 8; i++) r.u[i] = f2bf(sm[cg * 8 + i][l_loc]);
    *(uint4*)&xcb[(size_t)n * 1536 + c0 + cg * 8] = r.v;
  }
}

// ---------------- Kernel 2-fallback: conv + bias + SiLU (f32 only) ----------------
__global__ __launch_bounds__(256) void k_conv(
    const float* __restrict__ xb, const float* __restrict__ conv_w,
    const float* __restrict__ conv_b, float* __restrict__ xc) {
  int idx = blockIdx.x * 256 + threadIdx.x;   // B*C*L
  int l = idx % L_;
  int bc = idx / L_;
  int c = bc % C_;
  const float* xrow = xb + (size_t)bc * L_;
  const float* w = conv_w + c * K_;
  float acc = conv_b[c];
#pragma unroll
  for (int k = 0; k < K_; k++) {
    int ll = l - (K_ - 1) + k;
    if (ll >= 0) acc += xrow[ll] * w[k];
  }
  xc[idx] = acc / (1.f + __expf(-acc));
}

// ---------------- Kernel 3: x_dbl GEMM via MFMA ----------------
// out[m][n] = sum_c W[m][c] * xc[n][c];  m in [0,128), n = (b,l) in [0,1568)
// rows 0..95 -> dtt bf16 [n][96]; rows 96..111 -> Bt f32 [n][16]; 112..127 -> Ct.
// grid (25 n-tiles of 64, 8 m-tiles of 16); 4 waves, wave = n-subtile.
__global__ __launch_bounds__(256) void k_xdbl_mfma(
    const ushort_t* __restrict__ wxb,   // bf16 [128][1536]
    const ushort_t* __restrict__ xcb,   // bf16 [1600][1536]
    ushort_t* __restrict__ dtt,         // bf16 [1600][96]
    float* __restrict__ Bt, float* __restrict__ Ct) {
  __shared__ float sm[16][68];
  int tid = threadIdx.x;
  int wave = tid >> 6, lane = tid & 63;
  int n0 = blockIdx.x * 64;
  int m0 = blockIdx.y * 16;
  int row = lane & 15, kg = lane >> 4;
  f32x4 acc = {};
  const ushort_t* ap = wxb + (size_t)(m0 + row) * 1536 + kg * 8;
  const ushort_t* bp = xcb + (size_t)(n0 + wave * 16 + row) * 1536 + kg * 8;
#pragma unroll 8
  for (int ks = 0; ks < 48; ks++) {
    short8 a = *(const short8*)(ap + ks * 32);
    short8 b = *(const short8*)(bp + ks * 32);
    acc = __builtin_amdgcn_mfma_f32_16x16x32_bf16(a, b, acc, 0, 0, 0);
  }
#pragma unroll
  for (int j = 0; j < 4; j++)
    sm[kg * 4 + j][wave * 16 + row] = acc[j];
  __syncthreads();
  int n_loc = tid >> 2, mg = tid & 3;
  int n = n0 + n_loc;
  if (m0 < 96) {
    union { ushort_t u[4]; uint2 v; } r;
#pragma unroll
    for (int j = 0; j < 4; j++) r.u[j] = f2bf(sm[mg * 4 + j][n_loc]);
    *(uint2*)&dtt[(size_t)n * 96 + m0 + mg * 4] = r.v;
  } else if (n < BSZ * L_) {
    float4 v = {sm[mg * 4 + 0][n_loc], sm[mg * 4 + 1][n_loc],
                sm[mg * 4 + 2][n_loc], sm[mg * 4 + 3][n_loc]};
    float* dst = (m0 == 96) ? Bt : Ct;
    *(float4*)&dst[(size_t)n * 16 + mg * 4] = v;
  }
}

// ---------------- Kernel 3-fallback: x_dbl GEMM (f32) ----------------
__global__ __launch_bounds__(256) void k_xdbl_mono(
    const float* __restrict__ xc, const float* __restrict__ W,  // 128 x 1536
    float* __restrict__ xdbl, float* __restrict__ Bt, float* __restrict__ Ct) {
  int tx = threadIdx.x & 63;
  int ty = threadIdx.x >> 6;
  int l = blockIdx.x * 64 + tx;
  int r0 = blockIdx.y * 4 + ty;
  int r1 = r0 + 64;
  int b = blockIdx.z;
  if (l >= L_) return;
  const float* xcb2 = xc + (size_t)b * C_ * L_;
  float acc0 = 0.f, acc1 = 0.f;
#pragma unroll 4
  for (int c = 0; c < C_; c++) {
    float v = xcb2[(size_t)c * L_ + l];
    acc0 += v * W[(size_t)r0 * C_ + c];
    acc1 += v * W[(size_t)r1 * C_ + c];
  }
  xdbl[((size_t)b * 96 + r0) * L_ + l] = acc0;
  if (r1 < 96) {
    xdbl[((size_t)b * 96 + r1) * L_ + l] = acc1;
  } else if (r1 < 96 + N_) {
    Bt[((size_t)b * L_ + l) * N_ + (r1 - 96)] = acc1;
  } else {
    Ct[((size_t)b * L_ + l) * N_ + (r1 - 96 - N_)] = acc1;
  }
}

// ---------------- Kernel 4: delta GEMM via MFMA + bias + softplus ----------------
__global__ __launch_bounds__(256) void k_delta_mfma(
    const ushort_t* __restrict__ wdtb,   // bf16 [1536][96]
    const ushort_t* __restrict__ dtt,    // bf16 [1600][96]
    const float* __restrict__ dt_bias, float* __restrict__ delta) {
  __shared__ float smem[64][65];
  int tid = threadIdx.x;
  int wave = tid >> 6, lane = tid & 63;
  int n0 = blockIdx.x * 64;
  int c0b = blockIdx.y * 64;
  int row = lane & 15, kg = lane >> 4;
  int c0w = c0b + wave * 16;
  f32x4 acc[4] = {};
  const ushort_t* ap = wdtb + (size_t)(c0w + row) * 96 + kg * 8;
#pragma unroll
  for (int ks = 0; ks < 3; ks++) {
    short8 a = *(const short8*)(ap + ks * 32);
#pragma unroll
    for (int nt = 0; nt < 4; nt++) {
      short8 b = *(const short8*)(dtt + (size_t)(n0 + nt * 16 + row) * 96 + ks * 32 + kg * 8);
      acc[nt] = __builtin_amdgcn_mfma_f32_16x16x32_bf16(a, b, acc[nt], 0, 0, 0);
    }
  }
#pragma unroll
  for (int nt = 0; nt < 4; nt++)
#pragma unroll
    for (int j = 0; j < 4; j++)
      smem[wave * 16 + kg * 4 + j][nt * 16 + row] = acc[nt][j];
  __syncthreads();
  int c_loc = tid >> 2, q = tid & 3;
  int c = c0b + c_loc;
  float bias = dt_bias[c];
#pragma unroll
  for (int i = 0; i < 16; i++) {
    int nn = n0 + q * 16 + i;
    if (nn < BSZ * L_) {
      int b = nn / L_, l = nn - b * L_;
      float v = smem[c_loc][q * 16 + i] + bias;
      float sp = (v > 20.f) ? v : __logf(1.f + __expf(v));
      delta[((size_t)b * C_ + c) * L_ + l] = sp;
    }
  }
}

// ---------------- Kernel 4-fallback: delta GEMM + softplus (f32 LDS-tiled) ----------------
__global__ __launch_bounds__(256) void k_delta_gemm(
    const float* __restrict__ dtm, const float* __restrict__ Wdt,
    const float* __restrict__ dt_bias, float* __restrict__ delta) {
  __shared__ float Ws[96][68];
  __shared__ float Ds[96][68];
  int tid = threadIdx.x;
  int n0 = blockIdx.x * 64;
  int c0 = blockIdx.y * 64;
  for (int idx = tid; idx < 64 * 96; idx += 256) {
    int i = idx / 96, r = idx - i * 96;
    Ws[r][i] = Wdt[(size_t)(c0 + i) * 96 + r];
  }
  for (int idx = tid; idx < 96 * 64; idx += 256) {
    int r = idx >> 6, j = idx & 63;
    int n = n0 + j;
    float v = 0.f;
    if (n < BSZ * L_) {
      int b = n / L_, l = n - b * L_;
      v = dtm[((size_t)b * 96 + r) * L_ + l];
    }
    Ds[r][j] = v;
  }
  __syncthreads();
  int tx = tid & 15, ty = tid >> 4;
  float acc[4][4] = {};
#pragma unroll 8
  for (int r = 0; r < 96; r++) {
    float4 av = *(const float4*)&Ws[r][ty * 4];
    float4 bv = *(const float4*)&Ds[r][tx * 4];
    float a_[4] = {av.x, av.y, av.z, av.w};
    float b_[4] = {bv.x, bv.y, bv.z, bv.w};
#pragma unroll
    for (int i = 0; i < 4; i++)
#pragma unroll
      for (int j = 0; j < 4; j++) acc[i][j] += a_[i] * b_[j];
  }
#pragma unroll
  for (int i = 0; i < 4; i++) {
    int c = c0 + ty * 4 + i;
    float bias = dt_bias[c];
#pragma unroll
    for (int j = 0; j < 4; j++) {
      int n = n0 + tx * 4 + j;
      if (n < BSZ * L_) {
        int b = n / L_, l = n - b * L_;
        float v = acc[i][j] + bias;
        float sp = (v > 20.f) ? v : __logf(1.f + __expf(v));
        delta[((size_t)b * C_ + c) * L_ + l] = sp;
      }
    }
  }
}

// ---------------- Kernel 5: fused scan v3 ----------------
__global__ __launch_bounds__(512) void k_scan_fused(
    const float* __restrict__ delta, const float* __restrict__ xc,
    const float* __restrict__ zb, const float* __restrict__ Bt,
    const float* __restrict__ Ct, const float* __restrict__ A_log,
    const float* __restrict__ D_param, float* __restrict__ out) {
  __shared__ float BtS[196][20];
  __shared__ float CtS[196][20];
  __shared__ float yS[16][196];
  int tid = threadIdx.x;
  int b = blockIdx.y;
  int c_base = blockIdx.x * 16;
  int wave = tid >> 6, lane = tid & 63;
  int chunk = lane & 15;
  int nl = lane >> 4;
  bool act = chunk < 14;
  const int l0 = chunk * 14;
  int c0 = c_base + wave * 2;
  int c1 = c0 + 1;

  {
    const float4* gB = (const float4*)(Bt + (size_t)b * L_ * N_);
    const float4* gC = (const float4*)(Ct + (size_t)b * L_ * N_);
    for (int i = tid; i < 784; i += 512) {
      int l = i >> 2, q = i & 3;
      *(float4*)&BtS[l][q * 4] = gB[i];
      *(float4*)&CtS[l][q * 4] = gC[i];
    }
  }

  float4 a0, a1;
  {
    float4 t0 = *(const float4*)&A_log[c0 * N_ + nl * 4];
    float4 t1 = *(const float4*)&A_log[c1 * N_ + nl * 4];
    a0.x = -__expf(t0.x); a0.y = -__expf(t0.y);
    a0.z = -__expf(t0.z); a0.w = -__expf(t0.w);
    a1.x = -__expf(t1.x); a1.y = -__expf(t1.y);
    a1.z = -__expf(t1.z); a1.w = -__expf(t1.w);
  }
  size_t w0 = (size_t)(b * C_ + c0) * L_ + l0;
  size_t w1 = (size_t)(b * C_ + c1) * L_ + l0;

  float2 dv0[7], xv0[7], dv1[7], xv1[7];
  if (act) {
    const float2* d2a = (const float2*)(delta + w0);
    const float2* d2b = (const float2*)(delta + w1);
    const float2* x2a = (const float2*)(xc + w0);
    const float2* x2b = (const float2*)(xc + w1);
#pragma unroll
    for (int i = 0; i < 7; i++) {
      dv0[i] = d2a[i]; dv1[i] = d2b[i];
      xv0[i] = x2a[i]; xv1[i] = x2b[i];
    }
  } else {
#pragma unroll
    for (int i = 0; i < 7; i++) {
      dv0[i] = {0.f, 0.f}; dv1[i] = {0.f, 0.f};
      xv0[i] = {0.f, 0.f}; xv1[i] = {0.f, 0.f};
    }
  }
  __syncthreads();

  float4 h0 = {0.f,0.f,0.f,0.f}, p0 = {1.f,1.f,1.f,1.f};
  float4 h1 = {0.f,0.f,0.f,0.f}, p1 = {1.f,1.f,1.f,1.f};
#pragma unroll
  for (int l = 0; l < 14; l++) {
    float d0 = (l & 1) ? dv0[l >> 1].y : dv0[l >> 1].x;
    float d1 = (l & 1) ? dv1[l >> 1].y : dv1[l >> 1].x;
    float x0 = (l & 1) ? xv0[l >> 1].y : xv0[l >> 1].x;
    float x1 = (l & 1) ? xv1[l >> 1].y : xv1[l >> 1].x;
    float du0 = d0 * x0, du1 = d1 * x1;
    float4 Bv = *(const float4*)&BtS[l0 + l][nl * 4];
    float e0x = __expf(d0 * a0.x), e0y = __expf(d0 * a0.y);
    float e0z = __expf(d0 * a0.z), e0w = __expf(d0 * a0.w);
    float e1x = __expf(d1 * a1.x), e1y = __expf(d1 * a1.y);
    float e1z = __expf(d1 * a1.z), e1w = __expf(d1 * a1.w);
    h0.x = h0.x * e0x + du0 * Bv.x; p0.x *= e0x;
    h0.y = h0.y * e0y + du0 * Bv.y; p0.y *= e0y;
    h0.z = h0.z * e0z + du0 * Bv.z; p0.z *= e0z;
    h0.w = h0.w * e0w + du0 * Bv.w; p0.w *= e0w;
    h1.x = h1.x * e1x + du1 * Bv.x; p1.x *= e1x;
    h1.y = h1.y * e1y + du1 * Bv.y; p1.y *= e1y;
    h1.z = h1.z * e1z + du1 * Bv.z; p1.z *= e1z;
    h1.w = h1.w * e1w + du1 * Bv.w; p1.w *= e1w;
  }

#pragma unroll
  for (int s = 1; s < 16; s <<= 1) {
    float4 P0, Q0, P1, Q1;
    P0.x = __shfl_up(p0.x, s, 16); Q0.x = __shfl_up(h0.x, s, 16);
    P0.y = __shfl_up(p0.y, s, 16); Q0.y = __shfl_up(h0.y, s, 16);
    P0.z = __shfl_up(p0.z, s, 16); Q0.z = __shfl_up(h0.z, s, 16);
    P0.w = __shfl_up(p0.w, s, 16); Q0.w = __shfl_up(h0.w, s, 16);
    P1.x = __shfl_up(p1.x, s, 16); Q1.x = __shfl_up(h1.x, s, 16);
    P1.y = __shfl_up(p1.y, s, 16); Q1.y = __shfl_up(h1.y, s, 16);
    P1.z = __shfl_up(p1.z, s, 16); Q1.z = __shfl_up(h1.z, s, 16);
    P1.w = __shfl_up(p1.w, s, 16); Q1.w = __shfl_up(h1.w, s, 16);
    if (chunk >= s) {
      h0.x = p0.x * Q0.x + h0.x; p0.x *= P0.x;
      h0.y = p0.y * Q0.y + h0.y; p0.y *= P0.y;
      h0.z = p0.z * Q0.z + h0.z; p0.z *= P0.z;
      h0.w = p0.w * Q0.w + h0.w; p0.w *= P0.w;
      h1.x = p1.x * Q1.x + h1.x; p1.x *= P1.x;
      h1.y = p1.y * Q1.y + h1.y; p1.y *= P1.y;
      h1.z = p1.z * Q1.z + h1.z; p1.z *= P1.z;
      h1.w = p1.w * Q1.w + h1.w; p1.w *= P1.w;
    }
  }
  float4 g0, g1;
  g0.x = __shfl_up(h0.x, 1, 16); g1.x = __shfl_up(h1.x, 1, 16);
  g0.y = __shfl_up(h0.y, 1, 16); g1.y = __shfl_up(h1.y, 1, 16);
  g0.z = __shfl_up(h0.z, 1, 16); g1.z = __shfl_up(h1.z, 1, 16);
  g0.w = __shfl_up(h0.w, 1, 16); g1.w = __shfl_up(h1.w, 1, 16);
  if (chunk == 0) {
    g0.x = g0.y = g0.z = g0.w = 0.f;
    g1.x = g1.y = g1.z = g1.w = 0.f;
  }

  if (act) {
#pragma unroll
    for (int l = 0; l < 14; l++) {
      float d0 = (l & 1) ? dv0[l >> 1].y : dv0[l >> 1].x;
      float d1 = (l & 1) ? dv1[l >> 1].y : dv1[l >> 1].x;
      float x0 = (l & 1) ? xv0[l >> 1].y : xv0[l >> 1].x;
      float x1 = (l & 1) ? xv1[l >> 1].y : xv1[l >> 1].x;
      float du0 = d0 * x0, du1 = d1 * x1;
      float4 Bv = *(const float4*)&BtS[l0 + l][nl * 4];
      float4 Cv = *(const float4*)&CtS[l0 + l][nl * 4];
      float e0x = __expf(d0 * a0.x), e0y = __expf(d0 * a0.y);
      float e0z = __expf(d0 * a0.z), e0w = __expf(d0 * a0.w);
      float e1x = __expf(d1 * a1.x), e1y = __expf(d1 * a1.y);
      float e1z = __expf(d1 * a1.z), e1w = __expf(d1 * a1.w);
      g0.x = g0.x * e0x + du0 * Bv.x;
      g0.y = g0.y * e0y + du0 * Bv.y;
      g0.z = g0.z * e0z + du0 * Bv.z;
      g0.w = g0.w * e0w + du0 * Bv.w;
      g1.x = g1.x * e1x + du1 * Bv.x;
      g1.y = g1.y * e1y + du1 * Bv.y;
      g1.z = g1.z * e1z + du1 * Bv.z;
      g1.w = g1.w * e1w + du1 * Bv.w;
      float y0 = g0.x * Cv.x + g0.y * Cv.y + g0.z * Cv.z + g0.w * Cv.w;
      float y1 = g1.x * Cv.x + g1.y * Cv.y + g1.z * Cv.z + g1.w * Cv.w;
      y0 += __shfl_xor(y0, 16);
      y0 += __shfl_xor(y0, 32);
      y1 += __shfl_xor(y1, 16);
      y1 += __shfl_xor(y1, 32);
      if (nl == 0) {
        yS[wave * 2 + 0][l0 + l] = y0;
        yS[wave * 2 + 1][l0 + l] = y1;
      }
    }
  }
  __syncthreads();

  size_t base = (size_t)(b * C_ + c_base) * L_;   // 16 contiguous c-rows
  for (int idx = tid; idx < 16 * L_; idx += 512) {
    int cloc = idx / L_, l = idx - cloc * L_;
    float y = yS[cloc][l];
    float xv = xc[base + idx];
    float zv = zb[base + idx];
    float Dp = D_param[c_base + cloc];
    float sz = zv / (1.f + __expf(-zv));
    out[base + idx] = (y + xv * Dp) * sz;
  }
}

extern "C" void kernel_launch(void* const* d_in, const int* in_sizes, int n_in,
                              void* d_out, int out_size, void* d_ws, size_t ws_size,
                              hipStream_t stream) {
  const float* hidden    = (const float*)d_in[0];
  const float* in_proj_w = (const float*)d_in[1];
  const float* conv_w    = (const float*)d_in[2];
  const float* conv_b    = (const float*)d_in[3];
  const float* x_proj_w  = (const float*)d_in[4];
  const float* dt_proj_w = (const float*)d_in[5];
  const float* dt_bias   = (const float*)d_in[6];
  const float* A_log     = (const float*)d_in[7];
  const float* D_param   = (const float*)d_in[8];
  float* out = (float*)d_out;

  const size_t NBCL   = (size_t)BSZ * C_ * L_;        // 2408448
  const size_t NBT    = (size_t)BSZ * L_ * N_;        // 25088
  const size_t NHID   = (size_t)BSZ * T_ * L_ * D_;   // 2408448 elems
  const size_t NW1    = (size_t)2 * E_ * D_;          // 73728 elems
  const size_t NDTTF  = 76800;                        // 1600*96 bf16 (float units)
  const size_t NWDTF  = 73728;                        // 1536*96 bf16 (float units)
  const size_t NWXF   = 98304;                        // 128*1536 bf16 (float units)
  const size_t NXCBF  = 1228800;                      // 1600*1536 bf16 (float units)
  const size_t NCASTF = (NHID + NW1) / 2;             // 1241088
  float* ws = (float*)d_ws;
  float* xb    = ws;                 // later reused as delta
  float* zb    = xb + NBCL;
  float* xc    = zb + NBCL;
  float* BtArr = xc + NBCL;
  float* CtArr = BtArr + NBT;
  float* dttF  = CtArr + NBT;
  float* wdtbF = dttF + NDTTF;
  float* wxbF  = wdtbF + NWDTF;
  float* xcbF  = wxbF + NWXF;
  float* Pbuf  = xcbF + NXCBF;       // hb/wb casts (or fallback xdbl f32)
  float* delta = xb;

  size_t need = 3 * NBCL + 2 * NBT + NDTTF + NWDTF + NWXF + NXCBF + NCASTF;
  bool split_ok = ws_size / 4 >= need;

  if (split_ok) {
    ushort_t* hb   = (ushort_t*)Pbuf;
    ushort_t* wb   = hb + NHID;
    ushort_t* wdtb = (ushort_t*)wdtbF;
    ushort_t* wxb  = (ushort_t*)wxbF;
    ushort_t* dtt  = (ushort_t*)dttF;
    ushort_t* xcb  = (ushort_t*)xcbF;

    k_cast_all<<<1380, 256, 0, stream>>>(hidden, in_proj_w, dt_proj_w, x_proj_w,
                                         hb, wb, wdtb, wxb);
    k_inproj_mfma<<<dim3(196, 4), 256, 0, stream>>>(hb, wb, xb, zb);
    k_conv_cast<<<dim3(7, 24, BSZ), 256, 0, stream>>>(xb, conv_w, conv_b, xc, xcb);
    k_xdbl_mfma<<<dim3(25, 8), 256, 0, stream>>>(wxb, xcb, dtt, BtArr, CtArr);
    k_delta_mfma<<<dim3(25, 24), 256, 0, stream>>>(wdtb, dtt, dt_bias, delta);
    k_scan_fused<<<dim3(C_ / 16, BSZ), 512, 0, stream>>>(delta, xc, zb, BtArr, CtArr,
                                                         A_log, D_param, out);
  } else {
    // f32 fallback path
    float* xdblF = Pbuf;             // B*96*L f32
    k_inproj_f32<<<dim3(98, 3), 256, 0, stream>>>(hidden, in_proj_w, xb, zb);
    k_conv<<<(int)(NBCL / 256), 256, 0, stream>>>(xb, conv_w, conv_b, xc);
    k_xdbl_mono<<<dim3(4, 16, BSZ), 256, 0, stream>>>(xc, x_proj_w, xdblF, BtArr, CtArr);
    k_delta_gemm<<<dim3(25, 24), 256, 0, stream>>>(xdblF, dt_proj_w, dt_bias, delta);
    k_scan_fused<<<dim3(C_ / 16, BSZ), 512, 0, stream>>>(delta, xc, zb, BtArr, CtArr,
                                                         A_log, D_param, out);
  }
}

// Round 15
// 107.061 us; speedup vs baseline: 1.2472x; 1.2472x over previous
//
#include <hip/hip_runtime.h>
#include <hip/hip_bf16.h>
#include <cstddef>

// Problem constants
#define BSZ 8
#define T_  8
#define L_  196
#define D_  192
#define E_  192
#define C_  1536   // E*T
#define N_  16
#define K_  4
#define R_  96

typedef __attribute__((ext_vector_type(8))) short short8;
typedef __attribute__((ext_vector_type(4))) float f32x4;
typedef unsigned short ushort_t;

__device__ __forceinline__ ushort_t f2bf(float x) {
  unsigned int bits = __float_as_uint(x);
  bits += 0x7FFFu + ((bits >> 16) & 1u);   // RNE
  return (ushort_t)(bits >> 16);
}

// ---------------- Kernel 0: fused fp32 -> bf16 cast (hidden + in_proj_w + dt_proj_w) ----------------
__global__ __launch_bounds__(256) void k_cast_all(
    const float* __restrict__ hidden, const float* __restrict__ w,
    const float* __restrict__ wdt,
    ushort_t* __restrict__ hb, ushort_t* __restrict__ wb,
    ushort_t* __restrict__ wdtb) {
  const int H8 = 301056;           // 2408448/8
  const int W8 = H8 + 9216;        // + 73728/8
  const int T8 = W8 + 18432;       // + 147456/8
  int i = blockIdx.x * 256 + threadIdx.x;
  if (i >= T8) return;
  const float4* ip; uint4* op; int j;
  if (i < H8)      { ip = (const float4*)hidden; op = (uint4*)hb;   j = i; }
  else if (i < W8) { ip = (const float4*)w;      op = (uint4*)wb;   j = i - H8; }
  else             { ip = (const float4*)wdt;    op = (uint4*)wdtb; j = i - W8; }
  float4 v0 = ip[(size_t)j * 2];
  float4 v1 = ip[(size_t)j * 2 + 1];
  union { ushort_t u[8]; uint4 v; } r;
  float f[8] = {v0.x, v0.y, v0.z, v0.w, v1.x, v1.y, v1.z, v1.w};
#pragma unroll
  for (int k = 0; k < 8; k++) r.u[k] = f2bf(f[k]);
  op[j] = r.v;
}

// ---------------- Kernel 1: in_proj GEMM via MFMA (bf16) ----------------
__global__ __launch_bounds__(256) void k_inproj_mfma(
    const ushort_t* __restrict__ hb, const ushort_t* __restrict__ wb,
    float* __restrict__ xb, float* __restrict__ zb) {
  __shared__ float smem[64][97];
  int tid = threadIdx.x;
  int wave = tid >> 6, lane = tid & 63;
  int m0b = blockIdx.x * 64;
  int n0 = blockIdx.y * 96;
  int row = lane & 15, kg = lane >> 4;
  int m0w = m0b + wave * 16;

  f32x4 acc[6] = {};
  const ushort_t* ap = hb + (size_t)(m0w + row) * 192 + kg * 8;
#pragma unroll
  for (int ks = 0; ks < 6; ks++) {
    short8 a = *(const short8*)(ap + ks * 32);
#pragma unroll
    for (int nt = 0; nt < 6; nt++) {
      short8 b = *(const short8*)(wb + (size_t)(n0 + nt * 16 + row) * 192 + ks * 32 + kg * 8);
      acc[nt] = __builtin_amdgcn_mfma_f32_16x16x32_bf16(a, b, acc[nt], 0, 0, 0);
    }
  }
#pragma unroll
  for (int nt = 0; nt < 6; nt++) {
#pragma unroll
    for (int j = 0; j < 4; j++) {
      smem[wave * 16 + kg * 4 + j][nt * 16 + row] = acc[nt][j];
    }
  }
  __syncthreads();
  int mloc = tid & 63, eof = tid >> 6;
  int m_glob = m0b + mloc;
  int b = m_glob / 1568, u = m_glob % 1568;
  size_t obase = (size_t)b * 301056 + u;   // b*C*L + u
#pragma unroll
  for (int e = eof; e < 96; e += 4) {
    int eg = n0 + e;
    float v = smem[mloc][e];
    if (eg < 192) xb[obase + (size_t)eg * 1568] = v;
    else          zb[obase + (size_t)(eg - 192) * 1568] = v;
  }
}

// ---------------- Kernel 1-fallback: fp32 in_proj (128x128 tile) ----------------
__global__ __launch_bounds__(256) void k_inproj_f32(
    const float* __restrict__ A, const float* __restrict__ W,
    float* __restrict__ xb, float* __restrict__ zb) {
  __shared__ float As[16][132];
  __shared__ float Bs[16][132];
  int tid = threadIdx.x;
  int m0 = blockIdx.x * 128;
  int n0 = blockIdx.y * 128;
  int tx = tid & 15, ty = tid >> 4;
  float acc[8][8] = {};
  for (int k0 = 0; k0 < 192; k0 += 16) {
#pragma unroll
    for (int i = 0; i < 2; i++) {
      int idx = tid + i * 256;
      int m = idx >> 2, k4 = (idx & 3) * 4;
      float4 v = *(const float4*)&A[(size_t)(m0 + m) * 192 + k0 + k4];
      As[k4 + 0][m] = v.x; As[k4 + 1][m] = v.y;
      As[k4 + 2][m] = v.z; As[k4 + 3][m] = v.w;
    }
#pragma unroll
    for (int i = 0; i < 2; i++) {
      int idx = tid + i * 256;
      int n = idx >> 2, k4 = (idx & 3) * 4;
      float4 v = *(const float4*)&W[(size_t)(n0 + n) * 192 + k0 + k4];
      Bs[k4 + 0][n] = v.x; Bs[k4 + 1][n] = v.y;
      Bs[k4 + 2][n] = v.z; Bs[k4 + 3][n] = v.w;
    }
    __syncthreads();
#pragma unroll
    for (int kk = 0; kk < 16; kk++) {
      float a_[8], b_[8];
      *(float4*)&a_[0] = *(const float4*)&As[kk][ty * 4];
      *(float4*)&a_[4] = *(const float4*)&As[kk][ty * 4 + 64];
      *(float4*)&b_[0] = *(const float4*)&Bs[kk][tx * 4];
      *(float4*)&b_[4] = *(const float4*)&Bs[kk][tx * 4 + 64];
#pragma unroll
      for (int i = 0; i < 8; i++)
#pragma unroll
        for (int j = 0; j < 8; j++) acc[i][j] += a_[i] * b_[j];
    }
    __syncthreads();
  }
#pragma unroll
  for (int i = 0; i < 8; i++) {
    int m = m0 + ty * 4 + (i & 3) + ((i >> 2) * 64);
    int b = m / (T_ * L_);
    int r = m % (T_ * L_);
    int t = r / L_;
    int l = r % L_;
#pragma unroll
    for (int j = 0; j < 8; j++) {
      int e = n0 + tx * 4 + (j & 3) + ((j >> 2) * 64);
      float v = acc[i][j];
      if (e < E_) {
        int c = e * T_ + t;
        xb[((size_t)b * C_ + c) * L_ + l] = v;
      } else {
        int c = (e - E_) * T_ + t;
        zb[((size_t)b * C_ + c) * L_ + l] = v;
      }
    }
  }
}

// ---------------- Kernel 2 (fallback only): conv + bias + SiLU ----------------
__global__ __launch_bounds__(256) void k_conv(
    const float* __restrict__ xb, const float* __restrict__ conv_w,
    const float* __restrict__ conv_b, float* __restrict__ xc) {
  int idx = blockIdx.x * 256 + threadIdx.x;   // B*C*L
  int l = idx % L_;
  int bc = idx / L_;
  int c = bc % C_;
  const float* xrow = xb + (size_t)bc * L_;
  const float* w = conv_w + c * K_;
  float acc = conv_b[c];
#pragma unroll
  for (int k = 0; k < K_; k++) {
    int ll = l - (K_ - 1) + k;
    if (ll >= 0) acc += xrow[ll] * w[k];
  }
  xc[idx] = acc / (1.f + __expf(-acc));
}

// ---------------- Kernel 3: LDS-tiled split-K x_dbl GEMM, conv fused; writes xc byproduct ----------------
#define XKK 32
__global__ __launch_bounds__(256) void k_xdbl_tile(
    const float* __restrict__ xb, const float* __restrict__ conv_w,
    const float* __restrict__ conv_b, const float* __restrict__ W,  // 128 x 1536
    float* __restrict__ part, float* __restrict__ xcout) {
  __shared__ float Ws2[XKK][132];
  __shared__ float Xs[XKK][64];
  int tid = threadIdx.x;
  int n0 = blockIdx.x * 64;     // flattened (b,l) in [0,1568)
  int c0 = blockIdx.y * 96;     // K-chunk
  int tx = tid & 15, ty = tid >> 4;
  float acc[8][4] = {};
  for (int ck = 0; ck < 96; ck += XKK) {
#pragma unroll
    for (int p = 0; p < 4; p++) {
      int idx = tid + p * 256;
      int r = idx >> 3;
      int c4 = (idx & 7) * 4;
      float4 w4 = *(const float4*)&W[(size_t)r * 1536 + c0 + ck + c4];
      Ws2[c4 + 0][r] = w4.x; Ws2[c4 + 1][r] = w4.y;
      Ws2[c4 + 2][r] = w4.z; Ws2[c4 + 3][r] = w4.w;
    }
#pragma unroll
    for (int p = 0; p < 8; p++) {
      int idx = tid + p * 256;
      int c = idx >> 6, j = idx & 63;
      int n = n0 + j;
      float v = 0.f;
      if (n < BSZ * L_) {
        int b = n / L_, l = n - b * L_;
        int cc = c0 + ck + c;
        const float* row = xb + ((size_t)b * C_ + cc) * L_;
        float s = conv_b[cc];
#pragma unroll
        for (int k = 0; k < K_; k++) {
          int ll = l - 3 + k;
          if (ll >= 0) s += row[ll] * conv_w[cc * K_ + k];
        }
        v = s / (1.f + __expf(-s));
        xcout[((size_t)b * C_ + cc) * L_ + l] = v;
      }
      Xs[c][j] = v;
    }
    __syncthreads();
#pragma unroll
    for (int kk = 0; kk < XKK; kk++) {
      float w_[8], x_[4];
      *(float4*)&w_[0] = *(const float4*)&Ws2[kk][ty * 8];
      *(float4*)&w_[4] = *(const float4*)&Ws2[kk][ty * 8 + 4];
      *(float4*)&x_[0] = *(const float4*)&Xs[kk][tx * 4];
#pragma unroll
      for (int i = 0; i < 8; i++)
#pragma unroll
        for (int j = 0; j < 4; j++) acc[i][j] += w_[i] * x_[j];
    }
    __syncthreads();
  }
  int kc = blockIdx.y;
#pragma unroll
  for (int j = 0; j < 4; j++) {
    int n = n0 + tx * 4 + j;
    if (n < BSZ * L_) {
      int b = n / L_, l = n - b * L_;
      float* pp = &part[(((size_t)kc * 8 + b) * L_ + l) * 128 + ty * 8];
      float4 v0 = {acc[0][j], acc[1][j], acc[2][j], acc[3][j]};
      float4 v1 = {acc[4][j], acc[5][j], acc[6][j], acc[7][j]};
      *(float4*)&pp[0] = v0;
      *(float4*)&pp[4] = v1;
    }
  }
}

// ---------------- Kernel 3c: reduce partials -> dtt bf16 [n][96], Bt/Ct [b][l][16] ----------------
__global__ __launch_bounds__(256) void k_xreduce(
    const float* __restrict__ part, ushort_t* __restrict__ dtt,
    float* __restrict__ Bt, float* __restrict__ Ct) {
  int tx = threadIdx.x & 63;
  int ty = threadIdx.x >> 6;
  int l = blockIdx.x * 4 + ty;      // 49*4 = 196 exactly
  int b = blockIdx.y;
  size_t o = ((size_t)b * L_ + l) * 128 + tx;
  float v0 = 0.f, v1 = 0.f;
#pragma unroll
  for (int kc = 0; kc < 16; kc++) {
    v0 += part[(size_t)kc * (8 * L_ * 128) + o];
    v1 += part[(size_t)kc * (8 * L_ * 128) + o + 64];
  }
  int r1 = tx + 64;
  size_t nrow = ((size_t)b * L_ + l) * 96;
  dtt[nrow + tx] = f2bf(v0);
  if (r1 < 96) {
    dtt[nrow + r1] = f2bf(v1);
  } else if (r1 < 96 + N_) {
    Bt[((size_t)b * L_ + l) * N_ + (r1 - 96)] = v1;
  } else {
    Ct[((size_t)b * L_ + l) * N_ + (r1 - 96 - N_)] = v1;
  }
}

// ---------------- Kernel 3-mono (fallback): x_dbl GEMM (f32 dt out) ----------------
__global__ __launch_bounds__(256) void k_xdbl_mono(
    const float* __restrict__ xc, const float* __restrict__ W,  // 128 x 1536
    float* __restrict__ xdbl, float* __restrict__ Bt, float* __restrict__ Ct) {
  int tx = threadIdx.x & 63;
  int ty = threadIdx.x >> 6;
  int l = blockIdx.x * 64 + tx;
  int r0 = blockIdx.y * 4 + ty;
  int r1 = r0 + 64;
  int b = blockIdx.z;
  if (l >= L_) return;
  const float* xcb = xc + (size_t)b * C_ * L_;
  float acc0 = 0.f, acc1 = 0.f;
#pragma unroll 4
  for (int c = 0; c < C_; c++) {
    float v = xcb[(size_t)c * L_ + l];
    acc0 += v * W[(size_t)r0 * C_ + c];
    acc1 += v * W[(size_t)r1 * C_ + c];
  }
  xdbl[((size_t)b * 96 + r0) * L_ + l] = acc0;
  if (r1 < 96) {
    xdbl[((size_t)b * 96 + r1) * L_ + l] = acc1;
  } else if (r1 < 96 + N_) {
    Bt[((size_t)b * L_ + l) * N_ + (r1 - 96)] = acc1;
  } else {
    Ct[((size_t)b * L_ + l) * N_ + (r1 - 96 - N_)] = acc1;
  }
}

// ---------------- Kernel 4-fallback: delta GEMM + softplus (f32 LDS-tiled) ----------------
__global__ __launch_bounds__(256) void k_delta_gemm(
    const float* __restrict__ dtm, const float* __restrict__ Wdt,
    const float* __restrict__ dt_bias, float* __restrict__ delta) {
  __shared__ float Ws[96][68];
  __shared__ float Ds[96][68];
  int tid = threadIdx.x;
  int n0 = blockIdx.x * 64;
  int c0 = blockIdx.y * 64;
  for (int idx = tid; idx < 64 * 96; idx += 256) {
    int i = idx / 96, r = idx - i * 96;
    Ws[r][i] = Wdt[(size_t)(c0 + i) * 96 + r];
  }
  for (int idx = tid; idx < 96 * 64; idx += 256) {
    int r = idx >> 6, j = idx & 63;
    int n = n0 + j;
    float v = 0.f;
    if (n < BSZ * L_) {
      int b = n / L_, l = n - b * L_;
      v = dtm[((size_t)b * 96 + r) * L_ + l];
    }
    Ds[r][j] = v;
  }
  __syncthreads();
  int tx = tid & 15, ty = tid >> 4;
  float acc[4][4] = {};
#pragma unroll 8
  for (int r = 0; r < 96; r++) {
    float4 av = *(const float4*)&Ws[r][ty * 4];
    float4 bv = *(const float4*)&Ds[r][tx * 4];
    float a_[4] = {av.x, av.y, av.z, av.w};
    float b_[4] = {bv.x, bv.y, bv.z, bv.w};
#pragma unroll
    for (int i = 0; i < 4; i++)
#pragma unroll
      for (int j = 0; j < 4; j++) acc[i][j] += a_[i] * b_[j];
  }
#pragma unroll
  for (int i = 0; i < 4; i++) {
    int c = c0 + ty * 4 + i;
    float bias = dt_bias[c];
#pragma unroll
    for (int j = 0; j < 4; j++) {
      int n = n0 + tx * 4 + j;
      if (n < BSZ * L_) {
        int b = n / L_, l = n - b * L_;
        float v = acc[i][j] + bias;
        float sp = (v > 20.f) ? v : __logf(1.f + __expf(v));
        delta[((size_t)b * C_ + c) * L_ + l] = sp;
      }
    }
  }
}

// ---------------- Kernel 5: fused scan v5 (delta GEMM fused in-block) ----------------
// Block = 1 b x 16 c (8 waves x 2 c), 512 threads.
// Prologue: delta[16c x 196l] computed via MFMA from wdtb/dtt into dS (LDS).
// Then scan v3 structure: preload, pass1, Kogge-Stone, pass2, fused epilogue.
__global__ __launch_bounds__(512) void k_scan_fused(
    const float* __restrict__ xc, const float* __restrict__ zb,
    const float* __restrict__ Bt, const float* __restrict__ Ct,
    const float* __restrict__ A_log, const float* __restrict__ D_param,
    const ushort_t* __restrict__ wdtb,   // bf16 [1536][96]
    const ushort_t* __restrict__ dtt,    // bf16 [1600][96]
    const float* __restrict__ dt_bias, float* __restrict__ out) {
  __shared__ float BtS[196][20];
  __shared__ float CtS[196][20];
  __shared__ float yS[16][196];
  __shared__ float dS[16][200];
  int tid = threadIdx.x;
  int b = blockIdx.y;
  int c_base = blockIdx.x * 16;
  int wave = tid >> 6, lane = tid & 63;
  int chunk = lane & 15;
  int nl = lane >> 4;
  bool act = chunk < 14;
  const int l0 = chunk * 14;
  int c0 = c_base + wave * 2;
  int c1 = c0 + 1;

  // stage Bt[b], Ct[b]: coalesced
  {
    const float4* gB = (const float4*)(Bt + (size_t)b * L_ * N_);
    const float4* gC = (const float4*)(Ct + (size_t)b * L_ * N_);
    for (int i = tid; i < 784; i += 512) {
      int l = i >> 2, q = i & 3;
      *(float4*)&BtS[l][q * 4] = gB[i];
      *(float4*)&CtS[l][q * 4] = gC[i];
    }
  }

  // ---- in-block delta GEMM: dS[c_loc][l] = softplus(Wdt·dt + bias) ----
  // A = wdtb rows c_base..+16 (M=16), B = dtt rows b*196+nt*16.. (N), K=96.
  // C/D layout: col = lane&15 (n), row = (lane>>4)*4 + j (c_loc).
  {
    const ushort_t* ap2 = wdtb + (size_t)(c_base + chunk) * 96 + nl * 8;
    for (int nt = wave; nt < 13; nt += 8) {
      f32x4 accd = {};
      const ushort_t* bp2 = dtt + (size_t)(b * L_ + nt * 16 + chunk) * 96 + nl * 8;
#pragma unroll
      for (int ks = 0; ks < 3; ks++) {
        short8 a = *(const short8*)(ap2 + ks * 32);
        short8 bb = *(const short8*)(bp2 + ks * 32);
        accd = __builtin_amdgcn_mfma_f32_16x16x32_bf16(a, bb, accd, 0, 0, 0);
      }
      int lcol = nt * 16 + chunk;   // n within this b's 196
#pragma unroll
      for (int j = 0; j < 4; j++) {
        int c_loc = nl * 4 + j;
        if (lcol < L_) {
          float v = accd[j] + dt_bias[c_base + c_loc];
          dS[c_loc][lcol] = (v > 20.f) ? v : __logf(1.f + __expf(v));
        }
      }
    }
  }

  float4 a0, a1;
  {
    float4 t0 = *(const float4*)&A_log[c0 * N_ + nl * 4];
    float4 t1 = *(const float4*)&A_log[c1 * N_ + nl * 4];
    a0.x = -__expf(t0.x); a0.y = -__expf(t0.y);
    a0.z = -__expf(t0.z); a0.w = -__expf(t0.w);
    a1.x = -__expf(t1.x); a1.y = -__expf(t1.y);
    a1.z = -__expf(t1.z); a1.w = -__expf(t1.w);
  }
  size_t w0 = (size_t)(b * C_ + c0) * L_ + l0;
  size_t w1 = (size_t)(b * C_ + c1) * L_ + l0;

  // ---- preload xc for this chunk (global; overlaps with dS writes) ----
  float2 xv0[7], xv1[7];
  if (act) {
    const float2* x2a = (const float2*)(xc + w0);
    const float2* x2b = (const float2*)(xc + w1);
#pragma unroll
    for (int i = 0; i < 7; i++) { xv0[i] = x2a[i]; xv1[i] = x2b[i]; }
  } else {
#pragma unroll
    for (int i = 0; i < 7; i++) { xv0[i] = {0.f, 0.f}; xv1[i] = {0.f, 0.f}; }
  }
  __syncthreads();

  // ---- preload delta from dS ----
  float2 dv0[7], dv1[7];
  if (act) {
#pragma unroll
    for (int i = 0; i < 7; i++) {
      dv0[i] = *(const float2*)&dS[wave * 2 + 0][l0 + 2 * i];
      dv1[i] = *(const float2*)&dS[wave * 2 + 1][l0 + 2 * i];
    }
  } else {
#pragma unroll
    for (int i = 0; i < 7; i++) { dv0[i] = {0.f, 0.f}; dv1[i] = {0.f, 0.f}; }
  }

  // ---- pass 1: chunk-local (P, Q) for both c ----
  float4 h0 = {0.f,0.f,0.f,0.f}, p0 = {1.f,1.f,1.f,1.f};
  float4 h1 = {0.f,0.f,0.f,0.f}, p1 = {1.f,1.f,1.f,1.f};
#pragma unroll
  for (int l = 0; l < 14; l++) {
    float d0 = (l & 1) ? dv0[l >> 1].y : dv0[l >> 1].x;
    float d1 = (l & 1) ? dv1[l >> 1].y : dv1[l >> 1].x;
    float x0 = (l & 1) ? xv0[l >> 1].y : xv0[l >> 1].x;
    float x1 = (l & 1) ? xv1[l >> 1].y : xv1[l >> 1].x;
    float du0 = d0 * x0, du1 = d1 * x1;
    float4 Bv = *(const float4*)&BtS[l0 + l][nl * 4];
    float e0x = __expf(d0 * a0.x), e0y = __expf(d0 * a0.y);
    float e0z = __expf(d0 * a0.z), e0w = __expf(d0 * a0.w);
    float e1x = __expf(d1 * a1.x), e1y = __expf(d1 * a1.y);
    float e1z = __expf(d1 * a1.z), e1w = __expf(d1 * a1.w);
    h0.x = h0.x * e0x + du0 * Bv.x; p0.x *= e0x;
    h0.y = h0.y * e0y + du0 * Bv.y; p0.y *= e0y;
    h0.z = h0.z * e0z + du0 * Bv.z; p0.z *= e0z;
    h0.w = h0.w * e0w + du0 * Bv.w; p0.w *= e0w;
    h1.x = h1.x * e1x + du1 * Bv.x; p1.x *= e1x;
    h1.y = h1.y * e1y + du1 * Bv.y; p1.y *= e1y;
    h1.z = h1.z * e1z + du1 * Bv.z; p1.z *= e1z;
    h1.w = h1.w * e1w + du1 * Bv.w; p1.w *= e1w;
  }

  // ---- Kogge-Stone inclusive segmented scan (width 16) ----
#pragma unroll
  for (int s = 1; s < 16; s <<= 1) {
    float4 P0, Q0, P1, Q1;
    P0.x = __shfl_up(p0.x, s, 16); Q0.x = __shfl_up(h0.x, s, 16);
    P0.y = __shfl_up(p0.y, s, 16); Q0.y = __shfl_up(h0.y, s, 16);
    P0.z = __shfl_up(p0.z, s, 16); Q0.z = __shfl_up(h0.z, s, 16);
    P0.w = __shfl_up(p0.w, s, 16); Q0.w = __shfl_up(h0.w, s, 16);
    P1.x = __shfl_up(p1.x, s, 16); Q1.x = __shfl_up(h1.x, s, 16);
    P1.y = __shfl_up(p1.y, s, 16); Q1.y = __shfl_up(h1.y, s, 16);
    P1.z = __shfl_up(p1.z, s, 16); Q1.z = __shfl_up(h1.z, s, 16);
    P1.w = __shfl_up(p1.w, s, 16); Q1.w = __shfl_up(h1.w, s, 16);
    if (chunk >= s) {
      h0.x = p0.x * Q0.x + h0.x; p0.x *= P0.x;
      h0.y = p0.y * Q0.y + h0.y; p0.y *= P0.y;
      h0.z = p0.z * Q0.z + h0.z; p0.z *= P0.z;
      h0.w = p0.w * Q0.w + h0.w; p0.w *= P0.w;
      h1.x = p1.x * Q1.x + h1.x; p1.x *= P1.x;
      h1.y = p1.y * Q1.y + h1.y; p1.y *= P1.y;
      h1.z = p1.z * Q1.z + h1.z; p1.z *= P1.z;
      h1.w = p1.w * Q1.w + h1.w; p1.w *= P1.w;
    }
  }
  float4 g0, g1;
  g0.x = __shfl_up(h0.x, 1, 16); g1.x = __shfl_up(h1.x, 1, 16);
  g0.y = __shfl_up(h0.y, 1, 16); g1.y = __shfl_up(h1.y, 1, 16);
  g0.z = __shfl_up(h0.z, 1, 16); g1.z = __shfl_up(h1.z, 1, 16);
  g0.w = __shfl_up(h0.w, 1, 16); g1.w = __shfl_up(h1.w, 1, 16);
  if (chunk == 0) {
    g0.x = g0.y = g0.z = g0.w = 0.f;
    g1.x = g1.y = g1.z = g1.w = 0.f;
  }

  // ---- pass 2: true scan; park raw y = h.C in LDS ----
  if (act) {
#pragma unroll
    for (int l = 0; l < 14; l++) {
      float d0 = (l & 1) ? dv0[l >> 1].y : dv0[l >> 1].x;
      float d1 = (l & 1) ? dv1[l >> 1].y : dv1[l >> 1].x;
      float x0 = (l & 1) ? xv0[l >> 1].y : xv0[l >> 1].x;
      float x1 = (l & 1) ? xv1[l >> 1].y : xv1[l >> 1].x;
      float du0 = d0 * x0, du1 = d1 * x1;
      float4 Bv = *(const float4*)&BtS[l0 + l][nl * 4];
      float4 Cv = *(const float4*)&CtS[l0 + l][nl * 4];
      float e0x = __expf(d0 * a0.x), e0y = __expf(d0 * a0.y);
      float e0z = __expf(d0 * a0.z), e0w = __expf(d0 * a0.w);
      float e1x = __expf(d1 * a1.x), e1y = __expf(d1 * a1.y);
      float e1z = __expf(d1 * a1.z), e1w = __expf(d1 * a1.w);
      g0.x = g0.x * e0x + du0 * Bv.x;
      g0.y = g0.y * e0y + du0 * Bv.y;
      g0.z = g0.z * e0z + du0 * Bv.z;
      g0.w = g0.w * e0w + du0 * Bv.w;
      g1.x = g1.x * e1x + du1 * Bv.x;
      g1.y = g1.y * e1y + du1 * Bv.y;
      g1.z = g1.z * e1z + du1 * Bv.z;
      g1.w = g1.w * e1w + du1 * Bv.w;
      float y0 = g0.x * Cv.x + g0.y * Cv.y + g0.z * Cv.z + g0.w * Cv.w;
      float y1 = g1.x * Cv.x + g1.y * Cv.y + g1.z * Cv.z + g1.w * Cv.w;
      y0 += __shfl_xor(y0, 16);
      y0 += __shfl_xor(y0, 32);
      y1 += __shfl_xor(y1, 16);
      y1 += __shfl_xor(y1, 32);
      if (nl == 0) {
        yS[wave * 2 + 0][l0 + l] = y0;
        yS[wave * 2 + 1][l0 + l] = y1;
      }
    }
  }
  __syncthreads();

  // ---- coalesced fused epilogue ----
  size_t base = (size_t)(b * C_ + c_base) * L_;   // 16 contiguous c-rows
  for (int idx = tid; idx < 16 * L_; idx += 512) {
    int cloc = idx / L_, l = idx - cloc * L_;
    float y = yS[cloc][l];
    float xv = xc[base + idx];
    float zv = zb[base + idx];
    float Dp = D_param[c_base + cloc];
    float sz = zv / (1.f + __expf(-zv));
    out[base + idx] = (y + xv * Dp) * sz;
  }
}

// ---------------- Kernel 5-fallback: fused scan v3 (delta from global) ----------------
__global__ __launch_bounds__(512) void k_scan_f32(
    const float* __restrict__ delta, const float* __restrict__ xc,
    const float* __restrict__ zb, const float* __restrict__ Bt,
    const float* __restrict__ Ct, const float* __restrict__ A_log,
    const float* __restrict__ D_param, float* __restrict__ out) {
  __shared__ float BtS[196][20];
  __shared__ float CtS[196][20];
  __shared__ float yS[16][196];
  int tid = threadIdx.x;
  int b = blockIdx.y;
  int c_base = blockIdx.x * 16;
  int wave = tid >> 6, lane = tid & 63;
  int chunk = lane & 15;
  int nl = lane >> 4;
  bool act = chunk < 14;
  const int l0 = chunk * 14;
  int c0 = c_base + wave * 2;
  int c1 = c0 + 1;
  {
    const float4* gB = (const float4*)(Bt + (size_t)b * L_ * N_);
    const float4* gC = (const float4*)(Ct + (size_t)b * L_ * N_);
    for (int i = tid; i < 784; i += 512) {
      int l = i >> 2, q = i & 3;
      *(float4*)&BtS[l][q * 4] = gB[i];
      *(float4*)&CtS[l][q * 4] = gC[i];
    }
  }
  float4 a0, a1;
  {
    float4 t0 = *(const float4*)&A_log[c0 * N_ + nl * 4];
    float4 t1 = *(const float4*)&A_log[c1 * N_ + nl * 4];
    a0.x = -__expf(t0.x); a0.y = -__expf(t0.y);
    a0.z = -__expf(t0.z); a0.w = -__expf(t0.w);
    a1.x = -__expf(t1.x); a1.y = -__expf(t1.y);
    a1.z = -__expf(t1.z); a1.w = -__expf(t1.w);
  }
  size_t w0 = (size_t)(b * C_ + c0) * L_ + l0;
  size_t w1 = (size_t)(b * C_ + c1) * L_ + l0;
  float2 dv0[7], xv0[7], dv1[7], xv1[7];
  if (act) {
    const float2* d2a = (const float2*)(delta + w0);
    const float2* d2b = (const float2*)(delta + w1);
    const float2* x2a = (const float2*)(xc + w0);
    const float2* x2b = (const float2*)(xc + w1);
#pragma unroll
    for (int i = 0; i < 7; i++) {
      dv0[i] = d2a[i]; dv1[i] = d2b[i];
      xv0[i] = x2a[i]; xv1[i] = x2b[i];
    }
  } else {
#pragma unroll
    for (int i = 0; i < 7; i++) {
      dv0[i] = {0.f, 0.f}; dv1[i] = {0.f, 0.f};
      xv0[i] = {0.f, 0.f}; xv1[i] = {0.f, 0.f};
    }
  }
  __syncthreads();
  float4 h0 = {0.f,0.f,0.f,0.f}, p0 = {1.f,1.f,1.f,1.f};
  float4 h1 = {0.f,0.f,0.f,0.f}, p1 = {1.f,1.f,1.f,1.f};
#pragma unroll
  for (int l = 0; l < 14; l++) {
    float d0 = (l & 1) ? dv0[l >> 1].y : dv0[l >> 1].x;
    float d1 = (l & 1) ? dv1[l >> 1].y : dv1[l >> 1].x;
    float x0 = (l & 1) ? xv0[l >> 1].y : xv0[l >> 1].x;
    float x1 = (l & 1) ? xv1[l >> 1].y : xv1[l >> 1].x;
    float du0 = d0 * x0, du1 = d1 * x1;
    float4 Bv = *(const float4*)&BtS[l0 + l][nl * 4];
    float e0x = __expf(d0 * a0.x), e0y = __expf(d0 * a0.y);
    float e0z = __expf(d0 * a0.z), e0w = __expf(d0 * a0.w);
    float e1x = __expf(d1 * a1.x), e1y = __expf(d1 * a1.y);
    float e1z = __expf(d1 * a1.z), e1w = __expf(d1 * a1.w);
    h0.x = h0.x * e0x + du0 * Bv.x; p0.x *= e0x;
    h0.y = h0.y * e0y + du0 * Bv.y; p0.y *= e0y;
    h0.z = h0.z * e0z + du0 * Bv.z; p0.z *= e0z;
    h0.w = h0.w * e0w + du0 * Bv.w; p0.w *= e0w;
    h1.x = h1.x * e1x + du1 * Bv.x; p1.x *= e1x;
    h1.y = h1.y * e1y + du1 * Bv.y; p1.y *= e1y;
    h1.z = h1.z * e1z + du1 * Bv.z; p1.z *= e1z;
    h1.w = h1.w * e1w + du1 * Bv.w; p1.w *= e1w;
  }
#pragma unroll
  for (int s = 1; s < 16; s <<= 1) {
    float4 P0, Q0, P1, Q1;
    P0.x = __shfl_up(p0.x, s, 16); Q0.x = __shfl_up(h0.x, s, 16);
    P0.y = __shfl_up(p0.y, s, 16); Q0.y = __shfl_up(h0.y, s, 16);
    P0.z = __shfl_up(p0.z, s, 16); Q0.z = __shfl_up(h0.z, s, 16);
    P0.w = __shfl_up(p0.w, s, 16); Q0.w = __shfl_up(h0.w, s, 16);
    P1.x = __shfl_up(p1.x, s, 16); Q1.x = __shfl_up(h1.x, s, 16);
    P1.y = __shfl_up(p1.y, s, 16); Q1.y = __shfl_up(h1.y, s, 16);
    P1.z = __shfl_up(p1.z, s, 16); Q1.z = __shfl_up(h1.z, s, 16);
    P1.w = __shfl_up(p1.w, s, 16); Q1.w = __shfl_up(h1.w, s, 16);
    if (chunk >= s) {
      h0.x = p0.x * Q0.x + h0.x; p0.x *= P0.x;
      h0.y = p0.y * Q0.y + h0.y; p0.y *= P0.y;
      h0.z = p0.z * Q0.z + h0.z; p0.z *= P0.z;
      h0.w = p0.w * Q0.w + h0.w; p0.w *= P0.w;
      h1.x = p1.x * Q1.x + h1.x; p1.x *= P1.x;
      h1.y = p1.y * Q1.y + h1.y; p1.y *= P1.y;
      h1.z = p1.z * Q1.z + h1.z; p1.z *= P1.z;
      h1.w = p1.w * Q1.w + h1.w; p1.w *= P1.w;
    }
  }
  float4 g0, g1;
  g0.x = __shfl_up(h0.x, 1, 16); g1.x = __shfl_up(h1.x, 1, 16);
  g0.y = __shfl_up(h0.y, 1, 16); g1.y = __shfl_up(h1.y, 1, 16);
  g0.z = __shfl_up(h0.z, 1, 16); g1.z = __shfl_up(h1.z, 1, 16);
  g0.w = __shfl_up(h0.w, 1, 16); g1.w = __shfl_up(h1.w, 1, 16);
  if (chunk == 0) {
    g0.x = g0.y = g0.z = g0.w = 0.f;
    g1.x = g1.y = g1.z = g1.w = 0.f;
  }
  if (act) {
#pragma unroll
    for (int l = 0; l < 14; l++) {
      float d0 = (l & 1) ? dv0[l >> 1].y : dv0[l >> 1].x;
      float d1 = (l & 1) ? dv1[l >> 1].y : dv1[l >> 1].x;
      float x0 = (l & 1) ? xv0[l >> 1].y : xv0[l >> 1].x;
      float x1 = (l & 1) ? xv1[l >> 1].y : xv1[l >> 1].x;
      float du0 = d0 * x0, du1 = d1 * x1;
      float4 Bv = *(const float4*)&BtS[l0 + l][nl * 4];
      float4 Cv = *(const float4*)&CtS[l0 + l][nl * 4];
      float e0x = __expf(d0 * a0.x), e0y = __expf(d0 * a0.y);
      float e0z = __expf(d0 * a0.z), e0w = __expf(d0 * a0.w);
      float e1x = __expf(d1 * a1.x), e1y = __expf(d1 * a1.y);
      float e1z = __expf(d1 * a1.z), e1w = __expf(d1 * a1.w);
      g0.x = g0.x * e0x + du0 * Bv.x;
      g0.y = g0.y * e0y + du0 * Bv.y;
      g0.z = g0.z * e0z + du0 * Bv.z;
      g0.w = g0.w * e0w + du0 * Bv.w;
      g1.x = g1.x * e1x + du1 * Bv.x;
      g1.y = g1.y * e1y + du1 * Bv.y;
      g1.z = g1.z * e1z + du1 * Bv.z;
      g1.w = g1.w * e1w + du1 * Bv.w;
      float y0 = g0.x * Cv.x + g0.y * Cv.y + g0.z * Cv.z + g0.w * Cv.w;
      float y1 = g1.x * Cv.x + g1.y * Cv.y + g1.z * Cv.z + g1.w * Cv.w;
      y0 += __shfl_xor(y0, 16);
      y0 += __shfl_xor(y0, 32);
      y1 += __shfl_xor(y1, 16);
      y1 += __shfl_xor(y1, 32);
      if (nl == 0) {
        yS[wave * 2 + 0][l0 + l] = y0;
        yS[wave * 2 + 1][l0 + l] = y1;
      }
    }
  }
  __syncthreads();
  size_t base = (size_t)(b * C_ + c_base) * L_;
  for (int idx = tid; idx < 16 * L_; idx += 512) {
    int cloc = idx / L_, l = idx - cloc * L_;
    float y = yS[cloc][l];
    float xv = xc[base + idx];
    float zv = zb[base + idx];
    float Dp = D_param[c_base + cloc];
    float sz = zv / (1.f + __expf(-zv));
    out[base + idx] = (y + xv * Dp) * sz;
  }
}

extern "C" void kernel_launch(void* const* d_in, const int* in_sizes, int n_in,
                              void* d_out, int out_size, void* d_ws, size_t ws_size,
                              hipStream_t stream) {
  const float* hidden    = (const float*)d_in[0];
  const float* in_proj_w = (const float*)d_in[1];
  const float* conv_w    = (const float*)d_in[2];
  const float* conv_b    = (const float*)d_in[3];
  const float* x_proj_w  = (const float*)d_in[4];
  const float* dt_proj_w = (const float*)d_in[5];
  const float* dt_bias   = (const float*)d_in[6];
  const float* A_log     = (const float*)d_in[7];
  const float* D_param   = (const float*)d_in[8];
  float* out = (float*)d_out;

  const size_t NBCL   = (size_t)BSZ * C_ * L_;        // 2408448
  const size_t NBT    = (size_t)BSZ * L_ * N_;        // 25088
  const size_t NPART  = (size_t)16 * BSZ * L_ * 128;  // 3211264
  const size_t NHID   = (size_t)BSZ * T_ * L_ * D_;   // 2408448 elems
  const size_t NDTTF  = 76800;                        // 1600*96 bf16 (float units)
  const size_t NWDTF  = 73728;                        // 1536*96 bf16 (float units)
  float* ws = (float*)d_ws;
  float* xb    = ws;                 // fallback reuses as delta
  float* zb    = xb + NBCL;
  float* xc    = zb + NBCL;
  float* BtArr = xc + NBCL;
  float* CtArr = BtArr + NBT;
  float* dttF  = CtArr + NBT;        // bf16 dt^T [1600][96]
  float* wdtbF = dttF + NDTTF;       // bf16 Wdt
  float* Pbuf  = wdtbF + NWDTF;      // casts (hb/wb) then part
  float* delta = xb;

  size_t need = 3 * NBCL + 2 * NBT + NDTTF + NWDTF + NPART;
  bool split_ok = ws_size / 4 >= need;

  if (split_ok) {
    ushort_t* hb   = (ushort_t*)Pbuf;
    ushort_t* wb   = hb + NHID;
    ushort_t* wdtb = (ushort_t*)wdtbF;
    ushort_t* dtt  = (ushort_t*)dttF;
    float* part = Pbuf;              // clobbers hb/wb after inproj is done

    k_cast_all<<<1284, 256, 0, stream>>>(hidden, in_proj_w, dt_proj_w, hb, wb, wdtb);
    k_inproj_mfma<<<dim3(196, 4), 256, 0, stream>>>(hb, wb, xb, zb);
    k_xdbl_tile<<<dim3(25, 16), 256, 0, stream>>>(xb, conv_w, conv_b, x_proj_w, part, xc);
    k_xreduce<<<dim3(49, BSZ), 256, 0, stream>>>(part, dtt, BtArr, CtArr);
    k_scan_fused<<<dim3(C_ / 16, BSZ), 512, 0, stream>>>(xc, zb, BtArr, CtArr,
                                                         A_log, D_param,
                                                         wdtb, dtt, dt_bias, out);
  } else {
    // f32 fallback path
    float* xdblF = Pbuf;             // B*96*L f32
    k_inproj_f32<<<dim3(98, 3), 256, 0, stream>>>(hidden, in_proj_w, xb, zb);
    k_conv<<<(int)(NBCL / 256), 256, 0, stream>>>(xb, conv_w, conv_b, xc);
    k_xdbl_mono<<<dim3(4, 16, BSZ), 256, 0, stream>>>(xc, x_proj_w, xdblF, BtArr, CtArr);
    k_delta_gemm<<<dim3(25, 24), 256, 0, stream>>>(xdblF, dt_proj_w, dt_bias, delta);
    k_scan_f32<<<dim3(C_ / 16, BSZ), 512, 0, stream>>>(delta, xc, zb, BtArr, CtArr,
                                                       A_log, D_param, out);
  }
}